// Round 1
// baseline (3574.506 us; speedup 1.0000x reference)
//
#include <hip/hip_runtime.h>
#include <hip/hip_bf16.h>
#include <math.h>

// ---------------------------------------------------------------------------
// EvolveGCNH + GCNConv + EdgeDecoder, fp32 correctness-first implementation.
//
// Pipeline:
//  1) pnorm, score[i] = dot(x[i], p_pool)/||p||
//  2) exact top-256 (radix-select threshold + bitonic sort; ties -> lower idx)
//  3) x_tilde = x[perm] * tanh(top_score)
//  4) GRU step -> evolved W [256,256]
//  5) xw = x @ W              (fp32 tiled GEMM)
//  6) deg/dinv, scatter: node_emb[dst] += xw[src]*norm   (atomics)
//  7) A = node_emb @ W1a^T, B = node_emb @ W1b^T  (decoder lin1 split; A aliases xw)
//  8) pred[e] = relu(A[s]+B[t]+b1) . w2 + b2
// ---------------------------------------------------------------------------

__device__ __forceinline__ unsigned f2key(float f) {
  unsigned u = __float_as_uint(f);
  return (u & 0x80000000u) ? ~u : (u | 0x80000000u);
}

__global__ void pnorm_kernel(const float* __restrict__ p, float* __restrict__ out) {
  int lane = threadIdx.x;  // 64 threads
  float4 v = ((const float4*)p)[lane];
  float s = v.x * v.x + v.y * v.y + v.z * v.z + v.w * v.w;
#pragma unroll
  for (int off = 32; off > 0; off >>= 1) s += __shfl_down(s, off, 64);
  if (lane == 0) out[0] = sqrtf(s);
}

__global__ __launch_bounds__(256) void score_kernel(const float* __restrict__ x,
                                                    const float* __restrict__ p,
                                                    const float* __restrict__ pn,
                                                    float* __restrict__ score, int N) {
  int node = blockIdx.x * 4 + (threadIdx.x >> 6);
  int lane = threadIdx.x & 63;
  if (node >= N) return;
  float4 xv = ((const float4*)(x + (size_t)node * 256))[lane];
  float4 pv = ((const float4*)p)[lane];
  float s = xv.x * pv.x + xv.y * pv.y + xv.z * pv.z + xv.w * pv.w;
#pragma unroll
  for (int off = 32; off > 0; off >>= 1) s += __shfl_down(s, off, 64);
  if (lane == 0) score[node] = s / pn[0];
}

// Find key of k-th largest element (4x8-bit radix passes). out[0]=threshold key.
__global__ void radix_select_kernel(const float* __restrict__ score, int n, int k,
                                    unsigned* __restrict__ out) {
  __shared__ unsigned hist[256];
  __shared__ unsigned s_prefix;
  __shared__ int s_rem;
  int tid = threadIdx.x;
  if (tid == 0) { s_prefix = 0; s_rem = k; }
  __syncthreads();
  for (int pass = 0; pass < 4; ++pass) {
    hist[tid] = 0;
    __syncthreads();
    unsigned prefix = s_prefix;
    int shift = 24 - 8 * pass;
    for (int i = tid; i < n; i += 256) {
      unsigned key = f2key(score[i]);
      bool match = (pass == 0) || ((key >> (shift + 8)) == prefix);
      if (match) atomicAdd(&hist[(key >> shift) & 255u], 1u);
    }
    __syncthreads();
    if (tid == 0) {
      int rem = s_rem;
      int c = 0;
      int b = 255;
      for (; b > 0; --b) {
        int h = (int)hist[b];
        if (c + h >= rem) break;
        c += h;
      }
      s_prefix = (prefix << 8) | (unsigned)b;
      s_rem = rem - c;
    }
    __syncthreads();
  }
  if (tid == 0) { out[0] = s_prefix; out[1] = (unsigned)s_rem; }
}

// Collect all elements with key >= T (<=1024 barring mass ties), bitonic sort
// (key desc, idx asc), emit perm[k] and tanh(score) for the top-k.
__global__ __launch_bounds__(1024) void topk_collect_sort(const float* __restrict__ score, int n, int k,
                                                          const unsigned* __restrict__ sel,
                                                          int* __restrict__ perm,
                                                          float* __restrict__ tts) {
  __shared__ unsigned keys[1024];
  __shared__ int idxs[1024];
  __shared__ int cnt;
  int tid = threadIdx.x;
  unsigned T = sel[0];
  if (tid == 0) cnt = 0;
  keys[tid] = 0u;
  idxs[tid] = 0x7fffffff;
  __syncthreads();
  for (int i = tid; i < n; i += 1024) {
    unsigned key = f2key(score[i]);
    if (key >= T) {
      int p = atomicAdd(&cnt, 1);
      if (p < 1024) { keys[p] = key; idxs[p] = i; }
    }
  }
  __syncthreads();
  for (int size = 2; size <= 1024; size <<= 1) {
    for (int stride = size >> 1; stride > 0; stride >>= 1) {
      int j = tid ^ stride;
      if (j > tid) {
        unsigned ka = keys[tid], kb = keys[j];
        int ia = idxs[tid], ib = idxs[j];
        bool aBefore = (ka > kb) || (ka == kb && ia < ib);
        bool up = ((tid & size) == 0);
        if (aBefore != up) {
          keys[tid] = kb; keys[j] = ka;
          idxs[tid] = ib; idxs[j] = ia;
        }
      }
      __syncthreads();
    }
  }
  if (tid < k) {
    int idx = idxs[tid];
    perm[tid] = idx;
    tts[tid] = tanhf(score[idx]);
  }
}

__global__ void xtilde_kernel(const float* __restrict__ x, const int* __restrict__ perm,
                              const float* __restrict__ tts, float* __restrict__ xt) {
  int b = blockIdx.x, t = threadIdx.x;
  xt[b * 256 + t] = x[(size_t)perm[b] * 256 + t] * tts[b];
}

__global__ __launch_bounds__(256) void gru_kernel(const float* __restrict__ xt,
                                                  const float* __restrict__ Wi,
                                                  const float* __restrict__ W_ih,
                                                  const float* __restrict__ W_hh,
                                                  const float* __restrict__ b_ih,
                                                  const float* __restrict__ b_hh,
                                                  float* __restrict__ Wout) {
  int i = blockIdx.x, j = threadIdx.x;
  __shared__ float sx[256], sh[256];
  sx[j] = xt[i * 256 + j];
  sh[j] = Wi[i * 256 + j];
  __syncthreads();
  float gi[3], gh[3];
#pragma unroll
  for (int g = 0; g < 3; ++g) {
    int row = g * 256 + j;
    const float4* wi4 = (const float4*)(W_ih + (size_t)row * 256);
    const float4* wh4 = (const float4*)(W_hh + (size_t)row * 256);
    float si = 0.f, s2 = 0.f;
    for (int k4 = 0; k4 < 64; ++k4) {
      float4 wv = wi4[k4];
      float4 hv = wh4[k4];
      int k = k4 * 4;
      si += sx[k] * wv.x + sx[k + 1] * wv.y + sx[k + 2] * wv.z + sx[k + 3] * wv.w;
      s2 += sh[k] * hv.x + sh[k + 1] * hv.y + sh[k + 2] * hv.z + sh[k + 3] * hv.w;
    }
    gi[g] = si + b_ih[row];
    gh[g] = s2 + b_hh[row];
  }
  float r = 1.f / (1.f + expf(-(gi[0] + gh[0])));
  float z = 1.f / (1.f + expf(-(gi[1] + gh[1])));
  float nn = tanhf(gi[2] + r * gh[2]);
  Wout[i * 256 + j] = (1.f - z) * nn + z * sh[j];
}

// C[M,256] = A[M,256] @ B[256,256]; 64x64 tiles, BK=16, 4x4 per thread.
__global__ __launch_bounds__(256) void sgemm_256(const float* __restrict__ A,
                                                 const float* __restrict__ B,
                                                 float* __restrict__ C, int M) {
  const int N = 256, K = 256;
  __shared__ float As[16][64];
  __shared__ float Bs[16][64];
  int tid = threadIdx.x;
  int m0 = blockIdx.y * 64;
  int n0 = blockIdx.x * 64;
  int tm = tid >> 4, tn = tid & 15;
  int ar = tid >> 2;
  int ak = (tid & 3) * 4;
  int bkr = tid >> 4;
  int bnc = (tid & 15) * 4;
  float acc[4][4] = {{0.f}};
  for (int k0 = 0; k0 < K; k0 += 16) {
    float4 av = make_float4(0.f, 0.f, 0.f, 0.f);
    int row = m0 + ar;
    if (row < M) av = *(const float4*)(A + (size_t)row * K + k0 + ak);
    As[ak + 0][ar] = av.x;
    As[ak + 1][ar] = av.y;
    As[ak + 2][ar] = av.z;
    As[ak + 3][ar] = av.w;
    *(float4*)&Bs[bkr][bnc] = *(const float4*)(B + (size_t)(k0 + bkr) * N + n0 + bnc);
    __syncthreads();
#pragma unroll
    for (int kk = 0; kk < 16; ++kk) {
      float4 a = *(const float4*)&As[kk][tm * 4];
      float4 b = *(const float4*)&Bs[kk][tn * 4];
      float aa[4] = {a.x, a.y, a.z, a.w};
      float bb[4] = {b.x, b.y, b.z, b.w};
#pragma unroll
      for (int i = 0; i < 4; ++i)
#pragma unroll
        for (int j = 0; j < 4; ++j) acc[i][j] += aa[i] * bb[j];
    }
    __syncthreads();
  }
#pragma unroll
  for (int i = 0; i < 4; ++i) {
    int row = m0 + tm * 4 + i;
    if (row < M) {
      float4 v = make_float4(acc[i][0], acc[i][1], acc[i][2], acc[i][3]);
      *(float4*)(C + (size_t)row * N + n0 + tn * 4) = v;
    }
  }
}

__global__ void zero_kernel(float4* __restrict__ p, int n4) {
  int i = blockIdx.x * blockDim.x + threadIdx.x;
  if (i < n4) p[i] = make_float4(0.f, 0.f, 0.f, 0.f);
}

__global__ void deg_kernel(const int* __restrict__ ei, const float* __restrict__ attr,
                           float* __restrict__ deg, int E) {
  int e = blockIdx.x * blockDim.x + threadIdx.x;
  if (e < E) atomicAdd(&deg[ei[E + e]], attr[e]);
}

__global__ void dinv_kernel(const float* __restrict__ deg, float* __restrict__ dinv, int n) {
  int i = blockIdx.x * blockDim.x + threadIdx.x;
  if (i < n) {
    float d = deg[i];
    dinv[i] = d > 0.f ? 1.f / sqrtf(d) : 0.f;
  }
}

__global__ __launch_bounds__(256) void gcn_scatter(const float* __restrict__ xw,
                                                   const int* __restrict__ ei,
                                                   const float* __restrict__ attr,
                                                   const float* __restrict__ dinv,
                                                   float* __restrict__ ne, int E) {
  int e = blockIdx.x * 4 + (threadIdx.x >> 6);
  int lane = threadIdx.x & 63;
  if (e >= E) return;
  int s = ei[e], d = ei[E + e];
  float nrm = dinv[s] * attr[e] * dinv[d];
  float4 v = ((const float4*)(xw + (size_t)s * 256))[lane];
  float* o = ne + (size_t)d * 256 + (size_t)lane * 4;
  atomicAdd(o + 0, v.x * nrm);
  atomicAdd(o + 1, v.y * nrm);
  atomicAdd(o + 2, v.z * nrm);
  atomicAdd(o + 3, v.w * nrm);
}

__global__ void lin1_transpose(const float* __restrict__ lin1, float* __restrict__ WaT,
                               float* __restrict__ WbT) {
  int idx = blockIdx.x * 256 + threadIdx.x;  // 65536 total
  int kk = idx >> 8, n = idx & 255;
  WaT[kk * 256 + n] = lin1[n * 512 + kk];
  WbT[kk * 256 + n] = lin1[n * 512 + 256 + kk];
}

__global__ __launch_bounds__(256) void edge_decode(const float* __restrict__ A,
                                                   const float* __restrict__ Bm,
                                                   const int* __restrict__ ewi,
                                                   const float* __restrict__ b1,
                                                   const float* __restrict__ w2,
                                                   const float* __restrict__ b2,
                                                   float* __restrict__ out, int E) {
  int e = blockIdx.x * 4 + (threadIdx.x >> 6);
  int lane = threadIdx.x & 63;
  if (e >= E) return;
  int s = ewi[e], t = ewi[E + e];
  float4 a = ((const float4*)(A + (size_t)s * 256))[lane];
  float4 b = ((const float4*)(Bm + (size_t)t * 256))[lane];
  float4 bb = ((const float4*)b1)[lane];
  float4 w = ((const float4*)w2)[lane];
  float h0 = fmaxf(a.x + b.x + bb.x, 0.f);
  float h1 = fmaxf(a.y + b.y + bb.y, 0.f);
  float h2 = fmaxf(a.z + b.z + bb.z, 0.f);
  float h3 = fmaxf(a.w + b.w + bb.w, 0.f);
  float p = h0 * w.x + h1 * w.y + h2 * w.z + h3 * w.w;
#pragma unroll
  for (int off = 32; off > 0; off >>= 1) p += __shfl_down(p, off, 64);
  if (lane == 0) out[e] = p + b2[0];
}

extern "C" void kernel_launch(void* const* d_in, const int* in_sizes, int n_in,
                              void* d_out, int out_size, void* d_ws, size_t ws_size,
                              hipStream_t stream) {
  const float* x      = (const float*)d_in[0];
  const int*   ei     = (const int*)d_in[1];
  const float* attr   = (const float*)d_in[2];
  const int*   ewi    = (const int*)d_in[3];
  const float* p_pool = (const float*)d_in[4];
  const float* W_ih   = (const float*)d_in[5];
  const float* W_hh   = (const float*)d_in[6];
  const float* b_ih   = (const float*)d_in[7];
  const float* b_hh   = (const float*)d_in[8];
  const float* W_init = (const float*)d_in[9];
  const float* lin1_w = (const float*)d_in[10];
  const float* lin1_b = (const float*)d_in[11];
  const float* lin2_w = (const float*)d_in[12];
  const float* lin2_b = (const float*)d_in[13];
  float* out = (float*)d_out;

  const int C = 256;
  const int N = in_sizes[0] / C;   // 50000
  const int E = in_sizes[2];       // 800000

  // ---- workspace layout (256B aligned) ----
  char* ws = (char*)d_ws;
  size_t off = 0;
  auto alloc = [&](size_t bytes) {
    size_t o = off;
    off = (off + bytes + 255) & ~(size_t)255;
    return o;
  };
  float*    score = (float*)(ws + alloc((size_t)N * 4));
  float*    pnorm = (float*)(ws + alloc(4));
  unsigned* sel   = (unsigned*)(ws + alloc(8));
  int*      perm  = (int*)(ws + alloc(C * 4));
  float*    tts   = (float*)(ws + alloc(C * 4));
  float*    xt    = (float*)(ws + alloc((size_t)C * C * 4));
  float*    Wevo  = (float*)(ws + alloc((size_t)C * C * 4));
  float*    WaT   = (float*)(ws + alloc((size_t)C * C * 4));
  float*    WbT   = (float*)(ws + alloc((size_t)C * C * 4));
  float*    deg   = (float*)(ws + alloc((size_t)N * 4));
  float*    dinv  = (float*)(ws + alloc((size_t)N * 4));
  float*    xw    = (float*)(ws + alloc((size_t)N * C * 4));  // later reused as A
  float*    ne    = (float*)(ws + alloc((size_t)N * C * 4));
  float*    Bbuf  = (float*)(ws + alloc((size_t)N * C * 4));
  float*    Abuf  = xw;  // xw dead after scatter

  // 1) score
  pnorm_kernel<<<1, 64, 0, stream>>>(p_pool, pnorm);
  score_kernel<<<(N + 3) / 4, 256, 0, stream>>>(x, p_pool, pnorm, score, N);

  // 2) exact top-256 (sorted desc, ties -> lower index)
  radix_select_kernel<<<1, 256, 0, stream>>>(score, N, C, sel);
  topk_collect_sort<<<1, 1024, 0, stream>>>(score, N, C, sel, perm, tts);

  // 3) x_tilde
  xtilde_kernel<<<C, C, 0, stream>>>(x, perm, tts, xt);

  // 4) GRU -> evolved W
  gru_kernel<<<C, C, 0, stream>>>(xt, W_init, W_ih, W_hh, b_ih, b_hh, Wevo);

  // 5) xw = x @ Wevo
  {
    dim3 grid(C / 64, (N + 63) / 64);
    sgemm_256<<<grid, 256, 0, stream>>>(x, Wevo, xw, N);
  }

  // 6) GCN normalize + scatter
  zero_kernel<<<(N / 4 + 255) / 256, 256, 0, stream>>>((float4*)deg, N / 4);
  zero_kernel<<<((N * C / 4) + 255) / 256, 256, 0, stream>>>((float4*)ne, N * C / 4);
  deg_kernel<<<(E + 255) / 256, 256, 0, stream>>>(ei, attr, deg, E);
  dinv_kernel<<<(N + 255) / 256, 256, 0, stream>>>(deg, dinv, N);
  gcn_scatter<<<(E + 3) / 4, 256, 0, stream>>>(xw, ei, attr, dinv, ne, E);

  // 7) decoder lin1 split: A = ne @ W1a^T, B = ne @ W1b^T
  lin1_transpose<<<256, 256, 0, stream>>>(lin1_w, WaT, WbT);
  {
    dim3 grid(C / 64, (N + 63) / 64);
    sgemm_256<<<grid, 256, 0, stream>>>(ne, WaT, Abuf, N);
    sgemm_256<<<grid, 256, 0, stream>>>(ne, WbT, Bbuf, N);
  }

  // 8) edge decode
  edge_decode<<<(E + 3) / 4, 256, 0, stream>>>(Abuf, Bbuf, ewi, lin1_b, lin2_w, lin2_b, out, E);
}

// Round 2
// 1222.723 us; speedup vs baseline: 2.9234x; 2.9234x over previous
//
#include <hip/hip_runtime.h>
#include <hip/hip_bf16.h>
#include <math.h>

// ---------------------------------------------------------------------------
// EvolveGCNH + GCNConv + EdgeDecoder.
// R1 change: replace the 204.8M-float-atomic gcn_scatter (2650 us, atomic-RMW
// bound) with a dst-CSR build + register-accumulating gather (one wave/node,
// one 1KB row write per node).
// ---------------------------------------------------------------------------

__device__ __forceinline__ unsigned f2key(float f) {
  unsigned u = __float_as_uint(f);
  return (u & 0x80000000u) ? ~u : (u | 0x80000000u);
}

__global__ void pnorm_kernel(const float* __restrict__ p, float* __restrict__ out) {
  int lane = threadIdx.x;  // 64 threads
  float4 v = ((const float4*)p)[lane];
  float s = v.x * v.x + v.y * v.y + v.z * v.z + v.w * v.w;
#pragma unroll
  for (int off = 32; off > 0; off >>= 1) s += __shfl_down(s, off, 64);
  if (lane == 0) out[0] = sqrtf(s);
}

__global__ __launch_bounds__(256) void score_kernel(const float* __restrict__ x,
                                                    const float* __restrict__ p,
                                                    const float* __restrict__ pn,
                                                    float* __restrict__ score, int N) {
  int node = blockIdx.x * 4 + (threadIdx.x >> 6);
  int lane = threadIdx.x & 63;
  if (node >= N) return;
  float4 xv = ((const float4*)(x + (size_t)node * 256))[lane];
  float4 pv = ((const float4*)p)[lane];
  float s = xv.x * pv.x + xv.y * pv.y + xv.z * pv.z + xv.w * pv.w;
#pragma unroll
  for (int off = 32; off > 0; off >>= 1) s += __shfl_down(s, off, 64);
  if (lane == 0) score[node] = s / pn[0];
}

// Find key of k-th largest element (4x8-bit radix passes). out[0]=threshold key.
__global__ void radix_select_kernel(const float* __restrict__ score, int n, int k,
                                    unsigned* __restrict__ out) {
  __shared__ unsigned hist[256];
  __shared__ unsigned s_prefix;
  __shared__ int s_rem;
  int tid = threadIdx.x;
  if (tid == 0) { s_prefix = 0; s_rem = k; }
  __syncthreads();
  for (int pass = 0; pass < 4; ++pass) {
    hist[tid] = 0;
    __syncthreads();
    unsigned prefix = s_prefix;
    int shift = 24 - 8 * pass;
    for (int i = tid; i < n; i += 256) {
      unsigned key = f2key(score[i]);
      bool match = (pass == 0) || ((key >> (shift + 8)) == prefix);
      if (match) atomicAdd(&hist[(key >> shift) & 255u], 1u);
    }
    __syncthreads();
    if (tid == 0) {
      int rem = s_rem;
      int c = 0;
      int b = 255;
      for (; b > 0; --b) {
        int h = (int)hist[b];
        if (c + h >= rem) break;
        c += h;
      }
      s_prefix = (prefix << 8) | (unsigned)b;
      s_rem = rem - c;
    }
    __syncthreads();
  }
  if (tid == 0) { out[0] = s_prefix; out[1] = (unsigned)s_rem; }
}

// Collect all elements with key >= T (<=1024 barring mass ties), bitonic sort
// (key desc, idx asc), emit perm[k] and tanh(score) for the top-k.
__global__ __launch_bounds__(1024) void topk_collect_sort(const float* __restrict__ score, int n, int k,
                                                          const unsigned* __restrict__ sel,
                                                          int* __restrict__ perm,
                                                          float* __restrict__ tts) {
  __shared__ unsigned keys[1024];
  __shared__ int idxs[1024];
  __shared__ int cnt;
  int tid = threadIdx.x;
  unsigned T = sel[0];
  if (tid == 0) cnt = 0;
  keys[tid] = 0u;
  idxs[tid] = 0x7fffffff;
  __syncthreads();
  for (int i = tid; i < n; i += 1024) {
    unsigned key = f2key(score[i]);
    if (key >= T) {
      int p = atomicAdd(&cnt, 1);
      if (p < 1024) { keys[p] = key; idxs[p] = i; }
    }
  }
  __syncthreads();
  for (int size = 2; size <= 1024; size <<= 1) {
    for (int stride = size >> 1; stride > 0; stride >>= 1) {
      int j = tid ^ stride;
      if (j > tid) {
        unsigned ka = keys[tid], kb = keys[j];
        int ia = idxs[tid], ib = idxs[j];
        bool aBefore = (ka > kb) || (ka == kb && ia < ib);
        bool up = ((tid & size) == 0);
        if (aBefore != up) {
          keys[tid] = kb; keys[j] = ka;
          idxs[tid] = ib; idxs[j] = ia;
        }
      }
      __syncthreads();
    }
  }
  if (tid < k) {
    int idx = idxs[tid];
    perm[tid] = idx;
    tts[tid] = tanhf(score[idx]);
  }
}

__global__ void xtilde_kernel(const float* __restrict__ x, const int* __restrict__ perm,
                              const float* __restrict__ tts, float* __restrict__ xt) {
  int b = blockIdx.x, t = threadIdx.x;
  xt[b * 256 + t] = x[(size_t)perm[b] * 256 + t] * tts[b];
}

__global__ __launch_bounds__(256) void gru_kernel(const float* __restrict__ xt,
                                                  const float* __restrict__ Wi,
                                                  const float* __restrict__ W_ih,
                                                  const float* __restrict__ W_hh,
                                                  const float* __restrict__ b_ih,
                                                  const float* __restrict__ b_hh,
                                                  float* __restrict__ Wout) {
  int i = blockIdx.x, j = threadIdx.x;
  __shared__ float sx[256], sh[256];
  sx[j] = xt[i * 256 + j];
  sh[j] = Wi[i * 256 + j];
  __syncthreads();
  float gi[3], gh[3];
#pragma unroll
  for (int g = 0; g < 3; ++g) {
    int row = g * 256 + j;
    const float4* wi4 = (const float4*)(W_ih + (size_t)row * 256);
    const float4* wh4 = (const float4*)(W_hh + (size_t)row * 256);
    float si = 0.f, s2 = 0.f;
    for (int k4 = 0; k4 < 64; ++k4) {
      float4 wv = wi4[k4];
      float4 hv = wh4[k4];
      int k = k4 * 4;
      si += sx[k] * wv.x + sx[k + 1] * wv.y + sx[k + 2] * wv.z + sx[k + 3] * wv.w;
      s2 += sh[k] * hv.x + sh[k + 1] * hv.y + sh[k + 2] * hv.z + sh[k + 3] * hv.w;
    }
    gi[g] = si + b_ih[row];
    gh[g] = s2 + b_hh[row];
  }
  float r = 1.f / (1.f + expf(-(gi[0] + gh[0])));
  float z = 1.f / (1.f + expf(-(gi[1] + gh[1])));
  float nn = tanhf(gi[2] + r * gh[2]);
  Wout[i * 256 + j] = (1.f - z) * nn + z * sh[j];
}

// C[M,256] = A[M,256] @ B[256,256]; 64x64 tiles, BK=16, 4x4 per thread.
__global__ __launch_bounds__(256) void sgemm_256(const float* __restrict__ A,
                                                 const float* __restrict__ B,
                                                 float* __restrict__ C, int M) {
  const int N = 256, K = 256;
  __shared__ float As[16][64];
  __shared__ float Bs[16][64];
  int tid = threadIdx.x;
  int m0 = blockIdx.y * 64;
  int n0 = blockIdx.x * 64;
  int tm = tid >> 4, tn = tid & 15;
  int ar = tid >> 2;
  int ak = (tid & 3) * 4;
  int bkr = tid >> 4;
  int bnc = (tid & 15) * 4;
  float acc[4][4] = {{0.f}};
  for (int k0 = 0; k0 < K; k0 += 16) {
    float4 av = make_float4(0.f, 0.f, 0.f, 0.f);
    int row = m0 + ar;
    if (row < M) av = *(const float4*)(A + (size_t)row * K + k0 + ak);
    As[ak + 0][ar] = av.x;
    As[ak + 1][ar] = av.y;
    As[ak + 2][ar] = av.z;
    As[ak + 3][ar] = av.w;
    *(float4*)&Bs[bkr][bnc] = *(const float4*)(B + (size_t)(k0 + bkr) * N + n0 + bnc);
    __syncthreads();
#pragma unroll
    for (int kk = 0; kk < 16; ++kk) {
      float4 a = *(const float4*)&As[kk][tm * 4];
      float4 b = *(const float4*)&Bs[kk][tn * 4];
      float aa[4] = {a.x, a.y, a.z, a.w};
      float bb[4] = {b.x, b.y, b.z, b.w};
#pragma unroll
      for (int i = 0; i < 4; ++i)
#pragma unroll
        for (int j = 0; j < 4; ++j) acc[i][j] += aa[i] * bb[j];
    }
    __syncthreads();
  }
#pragma unroll
  for (int i = 0; i < 4; ++i) {
    int row = m0 + tm * 4 + i;
    if (row < M) {
      float4 v = make_float4(acc[i][0], acc[i][1], acc[i][2], acc[i][3]);
      *(float4*)(C + (size_t)row * N + n0 + tn * 4) = v;
    }
  }
}

__global__ void zero_kernel(float4* __restrict__ p, int n4) {
  int i = blockIdx.x * blockDim.x + threadIdx.x;
  if (i < n4) p[i] = make_float4(0.f, 0.f, 0.f, 0.f);
}

// counts[dst]++ and deg[dst] += attr, one pass over edges
__global__ void hist_deg_kernel(const int* __restrict__ ei, const float* __restrict__ attr,
                                int* __restrict__ cnt, float* __restrict__ deg, int E) {
  int e = blockIdx.x * blockDim.x + threadIdx.x;
  if (e < E) {
    int d = ei[E + e];
    atomicAdd(&cnt[d], 1);
    atomicAdd(&deg[d], attr[e]);
  }
}

__global__ void dinv_kernel(const float* __restrict__ deg, float* __restrict__ dinv, int n) {
  int i = blockIdx.x * blockDim.x + threadIdx.x;
  if (i < n) {
    float d = deg[i];
    dinv[i] = d > 0.f ? 1.f / sqrtf(d) : 0.f;
  }
}

// exclusive prefix sum of cnt[0..N) -> row_ptr[0..N], plus a second copy (cursor)
__global__ __launch_bounds__(1024) void scan_kernel(const int* __restrict__ cnt,
                                                    int* __restrict__ row_ptr,
                                                    int* __restrict__ cursor, int N) {
  __shared__ int ssum[1024];
  int tid = threadIdx.x;
  int chunk = (N + 1023) / 1024;
  int beg = tid * chunk;
  int end = beg + chunk < N ? beg + chunk : N;
  int s = 0;
  for (int i = beg; i < end; ++i) s += cnt[i];
  ssum[tid] = s;
  __syncthreads();
  for (int off = 1; off < 1024; off <<= 1) {
    int v = ssum[tid];
    int add = (tid >= off) ? ssum[tid - off] : 0;
    __syncthreads();
    ssum[tid] = v + add;
    __syncthreads();
  }
  int run = (tid == 0) ? 0 : ssum[tid - 1];
  for (int i = beg; i < end; ++i) {
    row_ptr[i] = run;
    cursor[i] = run;
    run += cnt[i];
  }
  if (tid == 1023) row_ptr[N] = run;
}

// CSR fill: es[pos] = src, ev[pos] = dinv[src]*attr (dst's dinv factored out)
__global__ void csr_fill_kernel(const int* __restrict__ ei, const float* __restrict__ attr,
                                const float* __restrict__ dinv, int* __restrict__ cursor,
                                int* __restrict__ es, float* __restrict__ ev, int E) {
  int e = blockIdx.x * blockDim.x + threadIdx.x;
  if (e < E) {
    int s = ei[e], d = ei[E + e];
    int pos = atomicAdd(&cursor[d], 1);
    es[pos] = s;
    ev[pos] = dinv[s] * attr[e];
  }
}

// one wave per dst node: acc(1KB row) in regs, single row write
__global__ __launch_bounds__(256) void gcn_gather(const float* __restrict__ xw,
                                                  const int* __restrict__ row_ptr,
                                                  const int* __restrict__ es,
                                                  const float* __restrict__ ev,
                                                  const float* __restrict__ dinv,
                                                  float* __restrict__ ne, int N) {
  int node = blockIdx.x * 4 + (threadIdx.x >> 6);
  int lane = threadIdx.x & 63;
  if (node >= N) return;
  int beg = row_ptr[node], end = row_ptr[node + 1];
  float ax = 0.f, ay = 0.f, az = 0.f, aw = 0.f;
  int j = beg;
  if (j < end) {
    int s = es[j];
    float v = ev[j];
    for (; j < end; ) {
      // prefetch next edge's metadata to break the dependent chain
      int ns = 0; float nv = 0.f;
      if (j + 1 < end) { ns = es[j + 1]; nv = ev[j + 1]; }
      float4 xv = ((const float4*)(xw + (size_t)s * 256))[lane];
      ax += xv.x * v; ay += xv.y * v; az += xv.z * v; aw += xv.w * v;
      s = ns; v = nv;
      ++j;
    }
  }
  float dd = dinv[node];
  float4 o = make_float4(ax * dd, ay * dd, az * dd, aw * dd);
  ((float4*)(ne + (size_t)node * 256))[lane] = o;
}

__global__ void lin1_transpose(const float* __restrict__ lin1, float* __restrict__ WaT,
                               float* __restrict__ WbT) {
  int idx = blockIdx.x * 256 + threadIdx.x;  // 65536 total
  int kk = idx >> 8, n = idx & 255;
  WaT[kk * 256 + n] = lin1[n * 512 + kk];
  WbT[kk * 256 + n] = lin1[n * 512 + 256 + kk];
}

__global__ __launch_bounds__(256) void edge_decode(const float* __restrict__ A,
                                                   const float* __restrict__ Bm,
                                                   const int* __restrict__ ewi,
                                                   const float* __restrict__ b1,
                                                   const float* __restrict__ w2,
                                                   const float* __restrict__ b2,
                                                   float* __restrict__ out, int E) {
  int e = blockIdx.x * 4 + (threadIdx.x >> 6);
  int lane = threadIdx.x & 63;
  if (e >= E) return;
  int s = ewi[e], t = ewi[E + e];
  float4 a = ((const float4*)(A + (size_t)s * 256))[lane];
  float4 b = ((const float4*)(Bm + (size_t)t * 256))[lane];
  float4 bb = ((const float4*)b1)[lane];
  float4 w = ((const float4*)w2)[lane];
  float h0 = fmaxf(a.x + b.x + bb.x, 0.f);
  float h1 = fmaxf(a.y + b.y + bb.y, 0.f);
  float h2 = fmaxf(a.z + b.z + bb.z, 0.f);
  float h3 = fmaxf(a.w + b.w + bb.w, 0.f);
  float p = h0 * w.x + h1 * w.y + h2 * w.z + h3 * w.w;
#pragma unroll
  for (int off = 32; off > 0; off >>= 1) p += __shfl_down(p, off, 64);
  if (lane == 0) out[e] = p + b2[0];
}

extern "C" void kernel_launch(void* const* d_in, const int* in_sizes, int n_in,
                              void* d_out, int out_size, void* d_ws, size_t ws_size,
                              hipStream_t stream) {
  const float* x      = (const float*)d_in[0];
  const int*   ei     = (const int*)d_in[1];
  const float* attr   = (const float*)d_in[2];
  const int*   ewi    = (const int*)d_in[3];
  const float* p_pool = (const float*)d_in[4];
  const float* W_ih   = (const float*)d_in[5];
  const float* W_hh   = (const float*)d_in[6];
  const float* b_ih   = (const float*)d_in[7];
  const float* b_hh   = (const float*)d_in[8];
  const float* W_init = (const float*)d_in[9];
  const float* lin1_w = (const float*)d_in[10];
  const float* lin1_b = (const float*)d_in[11];
  const float* lin2_w = (const float*)d_in[12];
  const float* lin2_b = (const float*)d_in[13];
  float* out = (float*)d_out;

  const int C = 256;
  const int N = in_sizes[0] / C;   // 50000
  const int E = in_sizes[2];       // 800000

  // ---- workspace layout (256B aligned) ----
  char* ws = (char*)d_ws;
  size_t off = 0;
  auto alloc = [&](size_t bytes) {
    size_t o = off;
    off = (off + bytes + 255) & ~(size_t)255;
    return o;
  };
  float*    score  = (float*)(ws + alloc((size_t)N * 4));
  float*    pnorm  = (float*)(ws + alloc(4));
  unsigned* sel    = (unsigned*)(ws + alloc(8));
  int*      perm   = (int*)(ws + alloc(C * 4));
  float*    tts    = (float*)(ws + alloc(C * 4));
  float*    xt     = (float*)(ws + alloc((size_t)C * C * 4));
  float*    Wevo   = (float*)(ws + alloc((size_t)C * C * 4));
  float*    WaT    = (float*)(ws + alloc((size_t)C * C * 4));
  float*    WbT    = (float*)(ws + alloc((size_t)C * C * 4));
  float*    deg    = (float*)(ws + alloc((size_t)N * 4));
  float*    dinv   = (float*)(ws + alloc((size_t)N * 4));
  int*      cnt    = (int*)(ws + alloc((size_t)N * 4));
  int*      rowp   = (int*)(ws + alloc((size_t)(N + 1) * 4));
  int*      cursor = (int*)(ws + alloc((size_t)N * 4));
  int*      es     = (int*)(ws + alloc((size_t)E * 4));
  float*    ev     = (float*)(ws + alloc((size_t)E * 4));
  float*    xw     = (float*)(ws + alloc((size_t)N * C * 4));  // later reused as A
  float*    ne     = (float*)(ws + alloc((size_t)N * C * 4));
  float*    Bbuf   = (float*)(ws + alloc((size_t)N * C * 4));
  float*    Abuf   = xw;  // xw dead after gather

  // 1) score
  pnorm_kernel<<<1, 64, 0, stream>>>(p_pool, pnorm);
  score_kernel<<<(N + 3) / 4, 256, 0, stream>>>(x, p_pool, pnorm, score, N);

  // 2) exact top-256 (sorted desc, ties -> lower index)
  radix_select_kernel<<<1, 256, 0, stream>>>(score, N, C, sel);
  topk_collect_sort<<<1, 1024, 0, stream>>>(score, N, C, sel, perm, tts);

  // 3) x_tilde
  xtilde_kernel<<<C, C, 0, stream>>>(x, perm, tts, xt);

  // 4) GRU -> evolved W
  gru_kernel<<<C, C, 0, stream>>>(xt, W_init, W_ih, W_hh, b_ih, b_hh, Wevo);

  // 5) xw = x @ Wevo
  {
    dim3 grid(C / 64, (N + 63) / 64);
    sgemm_256<<<grid, 256, 0, stream>>>(x, Wevo, xw, N);
  }

  // 6) GCN: build dst-CSR, then register-gather (no float atomics)
  zero_kernel<<<(N / 4 + 255) / 256, 256, 0, stream>>>((float4*)deg, N / 4);
  zero_kernel<<<(N / 4 + 255) / 256, 256, 0, stream>>>((float4*)cnt, N / 4);
  hist_deg_kernel<<<(E + 255) / 256, 256, 0, stream>>>(ei, attr, cnt, deg, E);
  dinv_kernel<<<(N + 255) / 256, 256, 0, stream>>>(deg, dinv, N);
  scan_kernel<<<1, 1024, 0, stream>>>(cnt, rowp, cursor, N);
  csr_fill_kernel<<<(E + 255) / 256, 256, 0, stream>>>(ei, attr, dinv, cursor, es, ev, E);
  gcn_gather<<<(N + 3) / 4, 256, 0, stream>>>(xw, rowp, es, ev, dinv, ne, N);

  // 7) decoder lin1 split: A = ne @ W1a^T, B = ne @ W1b^T
  lin1_transpose<<<256, 256, 0, stream>>>(lin1_w, WaT, WbT);
  {
    dim3 grid(C / 64, (N + 63) / 64);
    sgemm_256<<<grid, 256, 0, stream>>>(ne, WaT, Abuf, N);
    sgemm_256<<<grid, 256, 0, stream>>>(ne, WbT, Bbuf, N);
  }

  // 8) edge decode
  edge_decode<<<(E + 3) / 4, 256, 0, stream>>>(Abuf, Bbuf, ewi, lin1_b, lin2_w, lin2_b, out, E);
}

// Round 3
// 1095.661 us; speedup vs baseline: 3.2624x; 1.1160x over previous
//
#include <hip/hip_runtime.h>
#include <hip/hip_bf16.h>
#include <math.h>

// ---------------------------------------------------------------------------
// EvolveGCNH + GCNConv + EdgeDecoder.
// R1: atomic scatter -> dst-CSR register gather (3574 -> 1223 us).
// R3: (a) fp32 sgemm -> split-bf16 MFMA GEMM (Ah*Bh + Al*Bh + Ah*Bl, fp32 acc,
//         ~fp24 accuracy) for xw and the two decoder projections;
//     (b) decoder A/B matrices stored bf16 -> edge_decode traffic halved;
//     (c) gather epilogue emits ne as bf16 hi/lo split directly.
// ---------------------------------------------------------------------------

typedef __attribute__((ext_vector_type(8))) short bf16x8;
typedef __attribute__((ext_vector_type(4))) float f32x4;

__device__ __forceinline__ unsigned f2key(float f) {
  unsigned u = __float_as_uint(f);
  return (u & 0x80000000u) ? ~u : (u | 0x80000000u);
}

// round-to-nearest-even fp32 -> bf16 bits
__device__ __forceinline__ unsigned short f2bf(float f) {
  unsigned u = __float_as_uint(f);
  unsigned r = u + 0x7fffu + ((u >> 16) & 1u);
  return (unsigned short)(r >> 16);
}
__device__ __forceinline__ float bf2f(unsigned short h) {
  return __uint_as_float((unsigned)h << 16);
}

__global__ void pnorm_kernel(const float* __restrict__ p, float* __restrict__ out) {
  int lane = threadIdx.x;  // 64 threads
  float4 v = ((const float4*)p)[lane];
  float s = v.x * v.x + v.y * v.y + v.z * v.z + v.w * v.w;
#pragma unroll
  for (int off = 32; off > 0; off >>= 1) s += __shfl_down(s, off, 64);
  if (lane == 0) out[0] = sqrtf(s);
}

__global__ __launch_bounds__(256) void score_kernel(const float* __restrict__ x,
                                                    const float* __restrict__ p,
                                                    const float* __restrict__ pn,
                                                    float* __restrict__ score, int N) {
  int node = blockIdx.x * 4 + (threadIdx.x >> 6);
  int lane = threadIdx.x & 63;
  if (node >= N) return;
  float4 xv = ((const float4*)(x + (size_t)node * 256))[lane];
  float4 pv = ((const float4*)p)[lane];
  float s = xv.x * pv.x + xv.y * pv.y + xv.z * pv.z + xv.w * pv.w;
#pragma unroll
  for (int off = 32; off > 0; off >>= 1) s += __shfl_down(s, off, 64);
  if (lane == 0) score[node] = s / pn[0];
}

// Find key of k-th largest element (4x8-bit radix passes). out[0]=threshold key.
__global__ void radix_select_kernel(const float* __restrict__ score, int n, int k,
                                    unsigned* __restrict__ out) {
  __shared__ unsigned hist[256];
  __shared__ unsigned s_prefix;
  __shared__ int s_rem;
  int tid = threadIdx.x;
  if (tid == 0) { s_prefix = 0; s_rem = k; }
  __syncthreads();
  for (int pass = 0; pass < 4; ++pass) {
    hist[tid] = 0;
    __syncthreads();
    unsigned prefix = s_prefix;
    int shift = 24 - 8 * pass;
    for (int i = tid; i < n; i += 256) {
      unsigned key = f2key(score[i]);
      bool match = (pass == 0) || ((key >> (shift + 8)) == prefix);
      if (match) atomicAdd(&hist[(key >> shift) & 255u], 1u);
    }
    __syncthreads();
    if (tid == 0) {
      int rem = s_rem;
      int c = 0;
      int b = 255;
      for (; b > 0; --b) {
        int h = (int)hist[b];
        if (c + h >= rem) break;
        c += h;
      }
      s_prefix = (prefix << 8) | (unsigned)b;
      s_rem = rem - c;
    }
    __syncthreads();
  }
  if (tid == 0) { out[0] = s_prefix; out[1] = (unsigned)s_rem; }
}

// Collect all elements with key >= T (<=1024 barring mass ties), bitonic sort
// (key desc, idx asc), emit perm[k] and tanh(score) for the top-k.
__global__ __launch_bounds__(1024) void topk_collect_sort(const float* __restrict__ score, int n, int k,
                                                          const unsigned* __restrict__ sel,
                                                          int* __restrict__ perm,
                                                          float* __restrict__ tts) {
  __shared__ unsigned keys[1024];
  __shared__ int idxs[1024];
  __shared__ int cnt;
  int tid = threadIdx.x;
  unsigned T = sel[0];
  if (tid == 0) cnt = 0;
  keys[tid] = 0u;
  idxs[tid] = 0x7fffffff;
  __syncthreads();
  for (int i = tid; i < n; i += 1024) {
    unsigned key = f2key(score[i]);
    if (key >= T) {
      int p = atomicAdd(&cnt, 1);
      if (p < 1024) { keys[p] = key; idxs[p] = i; }
    }
  }
  __syncthreads();
  for (int size = 2; size <= 1024; size <<= 1) {
    for (int stride = size >> 1; stride > 0; stride >>= 1) {
      int j = tid ^ stride;
      if (j > tid) {
        unsigned ka = keys[tid], kb = keys[j];
        int ia = idxs[tid], ib = idxs[j];
        bool aBefore = (ka > kb) || (ka == kb && ia < ib);
        bool up = ((tid & size) == 0);
        if (aBefore != up) {
          keys[tid] = kb; keys[j] = ka;
          idxs[tid] = ib; idxs[j] = ia;
        }
      }
      __syncthreads();
    }
  }
  if (tid < k) {
    int idx = idxs[tid];
    perm[tid] = idx;
    tts[tid] = tanhf(score[idx]);
  }
}

__global__ void xtilde_kernel(const float* __restrict__ x, const int* __restrict__ perm,
                              const float* __restrict__ tts, float* __restrict__ xt) {
  int b = blockIdx.x, t = threadIdx.x;
  xt[b * 256 + t] = x[(size_t)perm[b] * 256 + t] * tts[b];
}

// GRU step; writes evolved W TRANSPOSED, split into bf16 hi/lo:
// WevoTh/l[n*256 + k] = split(W[k][n])
__global__ __launch_bounds__(256) void gru_kernel(const float* __restrict__ xt,
                                                  const float* __restrict__ Wi,
                                                  const float* __restrict__ W_ih,
                                                  const float* __restrict__ W_hh,
                                                  const float* __restrict__ b_ih,
                                                  const float* __restrict__ b_hh,
                                                  unsigned short* __restrict__ WevoTh,
                                                  unsigned short* __restrict__ WevoTl) {
  int i = blockIdx.x, j = threadIdx.x;  // i = k-row of W, j = n-col
  __shared__ float sx[256], sh[256];
  sx[j] = xt[i * 256 + j];
  sh[j] = Wi[i * 256 + j];
  __syncthreads();
  float gi[3], gh[3];
#pragma unroll
  for (int g = 0; g < 3; ++g) {
    int row = g * 256 + j;
    const float4* wi4 = (const float4*)(W_ih + (size_t)row * 256);
    const float4* wh4 = (const float4*)(W_hh + (size_t)row * 256);
    float si = 0.f, s2 = 0.f;
    for (int k4 = 0; k4 < 64; ++k4) {
      float4 wv = wi4[k4];
      float4 hv = wh4[k4];
      int k = k4 * 4;
      si += sx[k] * wv.x + sx[k + 1] * wv.y + sx[k + 2] * wv.z + sx[k + 3] * wv.w;
      s2 += sh[k] * hv.x + sh[k + 1] * hv.y + sh[k + 2] * hv.z + sh[k + 3] * hv.w;
    }
    gi[g] = si + b_ih[row];
    gh[g] = s2 + b_hh[row];
  }
  float r = 1.f / (1.f + expf(-(gi[0] + gh[0])));
  float z = 1.f / (1.f + expf(-(gi[1] + gh[1])));
  float nn = tanhf(gi[2] + r * gh[2]);
  float w = (1.f - z) * nn + z * sh[j];
  unsigned short h = f2bf(w);
  unsigned short l = f2bf(w - bf2f(h));
  WevoTh[(size_t)j * 256 + i] = h;
  WevoTl[(size_t)j * 256 + i] = l;
}

// split fp32 array into bf16 hi/lo (float4 per thread)
__global__ __launch_bounds__(256) void split_bf16_kernel(const float* __restrict__ in,
                                                         unsigned short* __restrict__ hi,
                                                         unsigned short* __restrict__ lo,
                                                         int n4) {
  int i = blockIdx.x * 256 + threadIdx.x;
  if (i >= n4) return;
  float4 v = ((const float4*)in)[i];
  ushort4 hv, lv;
  hv.x = f2bf(v.x); lv.x = f2bf(v.x - bf2f(hv.x));
  hv.y = f2bf(v.y); lv.y = f2bf(v.y - bf2f(hv.y));
  hv.z = f2bf(v.z); lv.z = f2bf(v.z - bf2f(hv.z));
  hv.w = f2bf(v.w); lv.w = f2bf(v.w - bf2f(hv.w));
  ((ushort4*)hi)[i] = hv;
  ((ushort4*)lo)[i] = lv;
}

// lin1_w [256][512] -> WAh/WAl/WBh/WBl each [256][256] at [n][k] (= B^T layout)
__global__ __launch_bounds__(256) void lin1_split_kernel(const float* __restrict__ lin1,
                                                         unsigned short* __restrict__ WAh,
                                                         unsigned short* __restrict__ WAl,
                                                         unsigned short* __restrict__ WBh,
                                                         unsigned short* __restrict__ WBl) {
  int idx = blockIdx.x * 256 + threadIdx.x;  // 131072 total
  int n = idx >> 9, k = idx & 511;
  float v = lin1[idx];
  unsigned short h = f2bf(v);
  unsigned short l = f2bf(v - bf2f(h));
  if (k < 256) {
    WAh[n * 256 + k] = h;
    WAl[n * 256 + k] = l;
  } else {
    WBh[n * 256 + (k - 256)] = h;
    WBl[n * 256 + (k - 256)] = l;
  }
}

// ---------------------------------------------------------------------------
// Split-bf16 MFMA GEMM: C[M,256] = A[M,256] @ B[256,256]
// A given as bf16 hi/lo (row-major); B given as B^T bf16 hi/lo (BT[n][k]).
// C = Ah*Bh + Al*Bh + Ah*Bl (fp32 accum) ~= fp32 GEMM to ~2^-17 rel.
// Block: 256 thr = 4 waves; block tile 64(M) x 256(N); wave w -> cols [64w,64w+64).
// Per wave: 4 m-tiles x 4 n-tiles of 16x16, K-loop step 32, no LDS (L1 reuse).
// mfma_f32_16x16x32_bf16 layouts (HW-verified per guide):
//   A-frag: A[m = lane&15][k = (lane>>4)*8 + j]
//   B-frag: B[k = (lane>>4)*8 + j][n = lane&15]  -> read BT[n][k] rows
//   C/D   : col = lane&15, row = (lane>>4)*4 + reg
// ---------------------------------------------------------------------------
template <typename OutT>
__global__ __launch_bounds__(256) void mfma_gemm_split(const unsigned short* __restrict__ Ah,
                                                       const unsigned short* __restrict__ Al,
                                                       const unsigned short* __restrict__ BTh,
                                                       const unsigned short* __restrict__ BTl,
                                                       OutT* __restrict__ Cout, int M) {
  int tid = threadIdx.x;
  int wave = tid >> 6, lane = tid & 63;
  int quad = lane >> 4, r16 = lane & 15;
  int n0 = wave * 64;
  int mbase = blockIdx.x * 64;

  f32x4 acc[4][4];
#pragma unroll
  for (int i = 0; i < 4; ++i)
#pragma unroll
    for (int j = 0; j < 4; ++j) acc[i][j] = (f32x4){0.f, 0.f, 0.f, 0.f};

  for (int k0 = 0; k0 < 256; k0 += 32) {
    int koff = k0 + quad * 8;
    bf16x8 ah[4], al[4], bh[4], bl[4];
#pragma unroll
    for (int mt = 0; mt < 4; ++mt) {
      int row = mbase + mt * 16 + r16;
      row = row < M ? row : M - 1;
      ah[mt] = *(const bf16x8*)(Ah + (size_t)row * 256 + koff);
      al[mt] = *(const bf16x8*)(Al + (size_t)row * 256 + koff);
    }
#pragma unroll
    for (int nt = 0; nt < 4; ++nt) {
      int nrow = n0 + nt * 16 + r16;
      bh[nt] = *(const bf16x8*)(BTh + (size_t)nrow * 256 + koff);
      bl[nt] = *(const bf16x8*)(BTl + (size_t)nrow * 256 + koff);
    }
#pragma unroll
    for (int mt = 0; mt < 4; ++mt)
#pragma unroll
      for (int nt = 0; nt < 4; ++nt) {
        acc[mt][nt] = __builtin_amdgcn_mfma_f32_16x16x32_bf16(ah[mt], bh[nt], acc[mt][nt], 0, 0, 0);
        acc[mt][nt] = __builtin_amdgcn_mfma_f32_16x16x32_bf16(al[mt], bh[nt], acc[mt][nt], 0, 0, 0);
        acc[mt][nt] = __builtin_amdgcn_mfma_f32_16x16x32_bf16(ah[mt], bl[nt], acc[mt][nt], 0, 0, 0);
      }
  }
#pragma unroll
  for (int mt = 0; mt < 4; ++mt) {
#pragma unroll
    for (int rr = 0; rr < 4; ++rr) {
      int grow = mbase + mt * 16 + quad * 4 + rr;
      if (grow < M) {
#pragma unroll
        for (int nt = 0; nt < 4; ++nt) {
          float v = acc[mt][nt][rr];
          size_t o = (size_t)grow * 256 + n0 + nt * 16 + r16;
          if constexpr (sizeof(OutT) == 4)
            ((float*)Cout)[o] = v;
          else
            ((unsigned short*)Cout)[o] = f2bf(v);
        }
      }
    }
  }
}

__global__ void zero_kernel(float4* __restrict__ p, int n4) {
  int i = blockIdx.x * blockDim.x + threadIdx.x;
  if (i < n4) p[i] = make_float4(0.f, 0.f, 0.f, 0.f);
}

// counts[dst]++ and deg[dst] += attr, one pass over edges
__global__ void hist_deg_kernel(const int* __restrict__ ei, const float* __restrict__ attr,
                                int* __restrict__ cnt, float* __restrict__ deg, int E) {
  int e = blockIdx.x * blockDim.x + threadIdx.x;
  if (e < E) {
    int d = ei[E + e];
    atomicAdd(&cnt[d], 1);
    atomicAdd(&deg[d], attr[e]);
  }
}

__global__ void dinv_kernel(const float* __restrict__ deg, float* __restrict__ dinv, int n) {
  int i = blockIdx.x * blockDim.x + threadIdx.x;
  if (i < n) {
    float d = deg[i];
    dinv[i] = d > 0.f ? 1.f / sqrtf(d) : 0.f;
  }
}

// exclusive prefix sum of cnt[0..N) -> row_ptr[0..N], plus a cursor copy
__global__ __launch_bounds__(1024) void scan_kernel(const int* __restrict__ cnt,
                                                    int* __restrict__ row_ptr,
                                                    int* __restrict__ cursor, int N) {
  __shared__ int ssum[1024];
  int tid = threadIdx.x;
  int chunk = (N + 1023) / 1024;
  int beg = tid * chunk;
  int end = beg + chunk < N ? beg + chunk : N;
  int s = 0;
  for (int i = beg; i < end; ++i) s += cnt[i];
  ssum[tid] = s;
  __syncthreads();
  for (int off = 1; off < 1024; off <<= 1) {
    int v = ssum[tid];
    int add = (tid >= off) ? ssum[tid - off] : 0;
    __syncthreads();
    ssum[tid] = v + add;
    __syncthreads();
  }
  int run = (tid == 0) ? 0 : ssum[tid - 1];
  for (int i = beg; i < end; ++i) {
    row_ptr[i] = run;
    cursor[i] = run;
    run += cnt[i];
  }
  if (tid == 1023) row_ptr[N] = run;
}

// CSR fill: es[pos] = src, ev[pos] = dinv[src]*attr (dst's dinv factored out)
__global__ void csr_fill_kernel(const int* __restrict__ ei, const float* __restrict__ attr,
                                const float* __restrict__ dinv, int* __restrict__ cursor,
                                int* __restrict__ es, float* __restrict__ ev, int E) {
  int e = blockIdx.x * blockDim.x + threadIdx.x;
  if (e < E) {
    int s = ei[e], d = ei[E + e];
    int pos = atomicAdd(&cursor[d], 1);
    es[pos] = s;
    ev[pos] = dinv[s] * attr[e];
  }
}

// one wave per dst node: acc(1KB row) in regs; epilogue writes ne split bf16 hi/lo
__global__ __launch_bounds__(256) void gcn_gather(const float* __restrict__ xw,
                                                  const int* __restrict__ row_ptr,
                                                  const int* __restrict__ es,
                                                  const float* __restrict__ ev,
                                                  const float* __restrict__ dinv,
                                                  unsigned short* __restrict__ neh,
                                                  unsigned short* __restrict__ nel, int N) {
  int node = blockIdx.x * 4 + (threadIdx.x >> 6);
  int lane = threadIdx.x & 63;
  if (node >= N) return;
  int beg = row_ptr[node], end = row_ptr[node + 1];
  float ax = 0.f, ay = 0.f, az = 0.f, aw = 0.f;
  int j = beg;
  if (j < end) {
    int s = es[j];
    float v = ev[j];
    for (; j < end;) {
      int ns = 0; float nv = 0.f;
      if (j + 1 < end) { ns = es[j + 1]; nv = ev[j + 1]; }
      float4 xv = ((const float4*)(xw + (size_t)s * 256))[lane];
      ax += xv.x * v; ay += xv.y * v; az += xv.z * v; aw += xv.w * v;
      s = ns; v = nv;
      ++j;
    }
  }
  float dd = dinv[node];
  float o0 = ax * dd, o1 = ay * dd, o2 = az * dd, o3 = aw * dd;
  ushort4 hv, lv;
  hv.x = f2bf(o0); lv.x = f2bf(o0 - bf2f(hv.x));
  hv.y = f2bf(o1); lv.y = f2bf(o1 - bf2f(hv.y));
  hv.z = f2bf(o2); lv.z = f2bf(o2 - bf2f(hv.z));
  hv.w = f2bf(o3); lv.w = f2bf(o3 - bf2f(hv.w));
  ((ushort4*)(neh + (size_t)node * 256))[lane] = hv;
  ((ushort4*)(nel + (size_t)node * 256))[lane] = lv;
}

// edge decode on bf16 A/B: pred[e] = relu(A[s]+B[t]+b1) . w2 + b2
__global__ __launch_bounds__(256) void edge_decode(const unsigned short* __restrict__ A,
                                                   const unsigned short* __restrict__ Bm,
                                                   const int* __restrict__ ewi,
                                                   const float* __restrict__ b1,
                                                   const float* __restrict__ w2,
                                                   const float* __restrict__ b2,
                                                   float* __restrict__ out, int E) {
  int e = blockIdx.x * 4 + (threadIdx.x >> 6);
  int lane = threadIdx.x & 63;
  if (e >= E) return;
  int s = ewi[e], t = ewi[E + e];
  ushort4 a4 = ((const ushort4*)(A + (size_t)s * 256))[lane];
  ushort4 b4 = ((const ushort4*)(Bm + (size_t)t * 256))[lane];
  float4 bb = ((const float4*)b1)[lane];
  float4 w = ((const float4*)w2)[lane];
  float h0 = fmaxf(bf2f(a4.x) + bf2f(b4.x) + bb.x, 0.f);
  float h1 = fmaxf(bf2f(a4.y) + bf2f(b4.y) + bb.y, 0.f);
  float h2 = fmaxf(bf2f(a4.z) + bf2f(b4.z) + bb.z, 0.f);
  float h3 = fmaxf(bf2f(a4.w) + bf2f(b4.w) + bb.w, 0.f);
  float p = h0 * w.x + h1 * w.y + h2 * w.z + h3 * w.w;
#pragma unroll
  for (int off = 32; off > 0; off >>= 1) p += __shfl_down(p, off, 64);
  if (lane == 0) out[e] = p + b2[0];
}

extern "C" void kernel_launch(void* const* d_in, const int* in_sizes, int n_in,
                              void* d_out, int out_size, void* d_ws, size_t ws_size,
                              hipStream_t stream) {
  const float* x      = (const float*)d_in[0];
  const int*   ei     = (const int*)d_in[1];
  const float* attr   = (const float*)d_in[2];
  const int*   ewi    = (const int*)d_in[3];
  const float* p_pool = (const float*)d_in[4];
  const float* W_ih   = (const float*)d_in[5];
  const float* W_hh   = (const float*)d_in[6];
  const float* b_ih   = (const float*)d_in[7];
  const float* b_hh   = (const float*)d_in[8];
  const float* W_init = (const float*)d_in[9];
  const float* lin1_w = (const float*)d_in[10];
  const float* lin1_b = (const float*)d_in[11];
  const float* lin2_w = (const float*)d_in[12];
  const float* lin2_b = (const float*)d_in[13];
  float* out = (float*)d_out;

  const int C = 256;
  const int N = in_sizes[0] / C;   // 50000
  const int E = in_sizes[2];       // 800000

  // ---- workspace layout (256B aligned) ----
  char* ws = (char*)d_ws;
  size_t off = 0;
  auto alloc = [&](size_t bytes) {
    size_t o = off;
    off = (off + bytes + 255) & ~(size_t)255;
    return o;
  };
  float*          score  = (float*)(ws + alloc((size_t)N * 4));
  float*          pnorm  = (float*)(ws + alloc(4));
  unsigned*       sel    = (unsigned*)(ws + alloc(8));
  int*            perm   = (int*)(ws + alloc(C * 4));
  float*          tts    = (float*)(ws + alloc(C * 4));
  float*          xt     = (float*)(ws + alloc((size_t)C * C * 4));
  unsigned short* WevoTh = (unsigned short*)(ws + alloc((size_t)C * C * 2));
  unsigned short* WevoTl = (unsigned short*)(ws + alloc((size_t)C * C * 2));
  unsigned short* WAh    = (unsigned short*)(ws + alloc((size_t)C * C * 2));
  unsigned short* WAl    = (unsigned short*)(ws + alloc((size_t)C * C * 2));
  unsigned short* WBh    = (unsigned short*)(ws + alloc((size_t)C * C * 2));
  unsigned short* WBl    = (unsigned short*)(ws + alloc((size_t)C * C * 2));
  float*          deg    = (float*)(ws + alloc((size_t)N * 4));
  float*          dinv   = (float*)(ws + alloc((size_t)N * 4));
  int*            cnt    = (int*)(ws + alloc((size_t)N * 4));
  int*            rowp   = (int*)(ws + alloc((size_t)(N + 1) * 4));
  int*            cursor = (int*)(ws + alloc((size_t)N * 4));
  int*            es     = (int*)(ws + alloc((size_t)E * 4));
  float*          ev     = (float*)(ws + alloc((size_t)E * 4));
  unsigned short* xh     = (unsigned short*)(ws + alloc((size_t)N * C * 2));
  unsigned short* xl     = (unsigned short*)(ws + alloc((size_t)N * C * 2));
  float*          xw     = (float*)(ws + alloc((size_t)N * C * 4));
  // aliases (producers/consumers strictly ordered):
  unsigned short* neh = xh;                                   // xh dead after GEMM1
  unsigned short* nel = xl;                                   // xl dead after GEMM1
  unsigned short* Abf = (unsigned short*)xw;                  // xw dead after gather
  unsigned short* Bbf = (unsigned short*)xw + (size_t)N * C;  // second half of xw region

  // 1) score
  pnorm_kernel<<<1, 64, 0, stream>>>(p_pool, pnorm);
  score_kernel<<<(N + 3) / 4, 256, 0, stream>>>(x, p_pool, pnorm, score, N);

  // 2) exact top-256 (sorted desc, ties -> lower index)
  radix_select_kernel<<<1, 256, 0, stream>>>(score, N, C, sel);
  topk_collect_sort<<<1, 1024, 0, stream>>>(score, N, C, sel, perm, tts);

  // 3) x_tilde
  xtilde_kernel<<<C, C, 0, stream>>>(x, perm, tts, xt);

  // 4) GRU -> evolved W (transposed, bf16 hi/lo)
  gru_kernel<<<C, C, 0, stream>>>(xt, W_init, W_ih, W_hh, b_ih, b_hh, WevoTh, WevoTl);

  // 5) xw = x @ Wevo via split-bf16 MFMA
  split_bf16_kernel<<<(N * C / 4 + 255) / 256, 256, 0, stream>>>(x, xh, xl, N * C / 4);
  mfma_gemm_split<float><<<(N + 63) / 64, 256, 0, stream>>>(xh, xl, WevoTh, WevoTl, xw, N);

  // 6) GCN: build dst-CSR, then register-gather (no float atomics)
  zero_kernel<<<(N / 4 + 255) / 256, 256, 0, stream>>>((float4*)deg, N / 4);
  zero_kernel<<<(N / 4 + 255) / 256, 256, 0, stream>>>((float4*)cnt, N / 4);
  hist_deg_kernel<<<(E + 255) / 256, 256, 0, stream>>>(ei, attr, cnt, deg, E);
  dinv_kernel<<<(N + 255) / 256, 256, 0, stream>>>(deg, dinv, N);
  scan_kernel<<<1, 1024, 0, stream>>>(cnt, rowp, cursor, N);
  csr_fill_kernel<<<(E + 255) / 256, 256, 0, stream>>>(ei, attr, dinv, cursor, es, ev, E);
  gcn_gather<<<(N + 3) / 4, 256, 0, stream>>>(xw, rowp, es, ev, dinv, neh, nel, N);

  // 7) decoder lin1 split GEMMs -> bf16 A/B (lin1_w rows ARE the B^T layout)
  lin1_split_kernel<<<(2 * C * C) / 256, 256, 0, stream>>>(lin1_w, WAh, WAl, WBh, WBl);
  mfma_gemm_split<unsigned short><<<(N + 63) / 64, 256, 0, stream>>>(neh, nel, WAh, WAl, Abf, N);
  mfma_gemm_split<unsigned short><<<(N + 63) / 64, 256, 0, stream>>>(neh, nel, WBh, WBl, Bbf, N);

  // 8) edge decode (bf16 operands)
  edge_decode<<<(E + 3) / 4, 256, 0, stream>>>(Abf, Bbf, ewi, lin1_b, lin2_w, lin2_b, out, E);
}